// Round 9
// baseline (2469.406 us; speedup 1.0000x reference)
//
#include <hip/hip_runtime.h>
#include <hip/hip_cooperative_groups.h>
#include <math.h>

namespace cgx = cooperative_groups;

typedef unsigned long long u64;
typedef unsigned int u32;

// SupervisedClusteringLoss via single cooperative Borůvka kernel.
// r7 post-mortem: scan was LDS-bank-conflict bound (2.86M conflicts, 688GB/s
// = 11% HBM) and rounds 2..7 re-read the full 64MB matrix. This version:
// (1) one cooperative kernel (grid.sync instead of ~27 launches),
// (2) per-row top-8 candidate lists -> rounds 2+ never touch the matrix
//     (exact: any edge < cand[7] is in the list; all-internal rows rescan),
// (3) conflict-free LDS packing (intents u8x4/dword, comp u16x2/dword).
// Loss invariance vs reference Prim: any MST under strict order (w,lo,hi)
// has the same weight multiset; obj depends only on weights (r7: absmax 0.0).

constexpr int N        = 4096;
constexpr int NB       = 256;    // blocks (1 per CU; coop-resident)
constexpr int NT       = 1024;   // threads per block
constexpr int EDGE_CAP = 4608;
constexpr int ROUNDS   = 16;     // loop breaks early when both graphs done
constexpr u64 SENT     = ~0ull;

__device__ __forceinline__ u32 mapf(float f) {
    u32 u = __float_as_uint(f);
    return (u & 0x80000000u) ? ~u : (u | 0x80000000u);
}
__device__ __forceinline__ float unmapf(u32 m) {
    u32 u = (m & 0x80000000u) ? (m ^ 0x80000000u) : ~m;
    return __uint_as_float(u);
}

#define INS_STEP(ci) { u64 lo = (ci < t) ? ci : t; u64 hi = (ci < t) ? t : ci; ci = lo; t = hi; }

__global__ __launch_bounds__(NT, 4)
void sc_loss_kernel(const float* __restrict__ S, const int* __restrict__ intents,
                    double* __restrict__ stats, u64* __restrict__ mk,
                    u64* __restrict__ cand, int* __restrict__ comp,
                    int* __restrict__ finalf, int* __restrict__ done,
                    float* __restrict__ out)
{
    const int bid  = blockIdx.x, tid = threadIdx.x;
    const int lane = tid & 63,   wid = tid >> 6;
    cgx::grid_group grid = cgx::this_grid();

    __shared__ union {
        struct { unsigned short cmp[N]; u32 ints[N/4]; } scan;   // 8K + 4K
        struct { u32 ints[N/4]; } build;                          // 4K
        struct { int par[N]; } merge;                             // 16K
    } u;
    __shared__ u64 s_edge[EDGE_CAP];      // per-graph edge list (driver blocks 0/1)
    __shared__ int s_ecnt;
    __shared__ int s_goldact;
    __shared__ int s_stalecnt;
    __shared__ unsigned short s_stale[16];
    __shared__ double s_red[16][3];

    // ---------------- init ----------------
    for (int t = bid * NT + tid; t < 2 * N; t += NB * NT) {
        mk[t] = SENT; comp[t] = t & (N - 1); finalf[t] = 0;
    }
    if (bid == 0) { if (tid < 8) stats[tid] = 0.0; if (tid < 2) done[tid] = 0; }
    if (tid == 0) { s_ecnt = 0; s_goldact = 0; }
    __threadfence(); grid.sync(); __threadfence();

    // ---------------- candidate build (one full matrix pass) ----------------
    const int i0 = intents[0];
    for (int d = tid; d < N / 4; d += NT) {
        const int4 v = *(const int4*)(intents + 4 * d);
        u.build.ints[d] = (u32)(v.x & 255) | ((u32)(v.y & 255) << 8) |
                          ((u32)(v.z & 255) << 16) | ((u32)(v.w & 255) << 24);
    }
    __syncthreads();
    const int row  = bid * 16 + wid;                 // one wave per row
    const int myii = (int)((u.build.ints[row >> 2] >> ((row & 3) * 8)) & 255u);
    if (myii == i0 && lane == 0) s_goldact = 1;      // benign race, all write 1
    const float* Srow = S + (size_t)row * N;

    for (int g = 0; g < 2; ++g) {
        u64* cp = cand + ((size_t)(g * N + row)) * 8;
        if (g == 0 && myii != i0) {                  // gold: only node-0's class matters
            if (lane == 0) {
                #pragma unroll
                for (int i = 0; i < 8; ++i) {
                    cp[i] = SENT;
                }
            }
            continue;
        }
        u64 c0=SENT,c1=SENT,c2=SENT,c3=SENT,c4=SENT,c5=SENT,c6=SENT,c7=SENT;
        for (int k = 0; k < 16; ++k) {
            const float4 f4 = *(const float4*)(Srow + k * 256 + lane * 4);
            const u32 ip    = u.build.ints[k * 64 + lane];      // 4 intents, conflict-free
            const float sv[4] = {f4.x, f4.y, f4.z, f4.w};
            #pragma unroll
            for (int m = 0; m < 4; ++m) {
                const int j   = k * 256 + lane * 4 + m;
                const bool eq = (int)((ip >> (8 * m)) & 255u) == myii;
                float w2; bool ex;
                if (g == 0) { w2 = -sv[m]; ex = eq && (sv[m] != 0.0f); }
                else { const float v = (sv[m] + (eq ? 0.0f : 0.5f)) - (eq ? 1.0f : 0.0f);
                       w2 = -v; ex = (v > 0.0f); }
                ex = ex && (j != row);
                const u64 key = ex ? (((u64)mapf(w2) << 32) | (u32)j) : SENT;
                if (key < c7) {                       // streaming sorted-insert top-8
                    u64 t = key;
                    INS_STEP(c0) INS_STEP(c1) INS_STEP(c2) INS_STEP(c3)
                    INS_STEP(c4) INS_STEP(c5) INS_STEP(c6) INS_STEP(c7)
                }
            }
        }
        // extract row top-8 ascending (wave min + pop), store to global
        #pragma unroll
        for (int i = 0; i < 8; ++i) {
            u64 m = c0;
            #pragma unroll
            for (int d2 = 1; d2 < 64; d2 <<= 1) { const u64 o = __shfl_xor(m, d2, 64); if (o < m) m = o; }
            if (c0 == m) { c0=c1; c1=c2; c2=c3; c3=c4; c4=c5; c5=c6; c6=c7; c7=SENT; }
            if (lane == 0) cp[i] = m;
        }
    }
    __threadfence(); grid.sync(); __threadfence();

    // ---------------- Borůvka rounds (matrix-free except rare rescans) ----------------
    for (int r = 0; r < ROUNDS; ++r) {
        const int d0 = done[0], d1 = done[1];
        if (d0 && d1) break;                          // uniform across grid

        for (int g = 0; g < 2; ++g) {
            if (g ? d1 : d0) continue;
            if (g == 0 && !s_goldact) continue;       // block-uniform skip
            // stage comp (u16 pairs) + intents (u8 quads) -- conflict-free reads
            for (int d = tid; d < N / 2; d += NT) {
                const int2 cpr = *(const int2*)(comp + g * N + 2 * d);
                ((u32*)u.scan.cmp)[d] = (u32)(cpr.x & 0xFFFF) | ((u32)(cpr.y & 0xFFFF) << 16);
            }
            for (int d = tid; d < N / 4; d += NT) {
                const int4 v = *(const int4*)(intents + 4 * d);
                u.scan.ints[d] = (u32)(v.x & 255) | ((u32)(v.y & 255) << 8) |
                                 ((u32)(v.z & 255) << 16) | ((u32)(v.w & 255) << 24);
            }
            if (tid == 0) s_stalecnt = 0;
            __syncthreads();

            // cand-scan: thread t<16 owns row bid*16+t
            if (tid < 16) {
                const int rw  = bid * 16 + tid;
                const int c_r = (int)u.scan.cmp[rw];
                if (!finalf[g * N + c_r]) {
                    const u64* cp = cand + ((size_t)(g * N + rw)) * 8;
                    u64 kk[8];
                    #pragma unroll
                    for (int i = 0; i < 8; ++i) kk[i] = cp[i];
                    u64 ksel = SENT; bool end = false;
                    #pragma unroll
                    for (int i = 0; i < 8; ++i) {
                        const u64 k = kk[i];
                        const bool isS = (k == SENT);
                        if (!end && !isS && ksel == SENT) {
                            const int j = (int)(k & 0xFFFFFFFFu);
                            if ((int)u.scan.cmp[j] != c_r) ksel = k;
                        }
                        end = end || isS;
                    }
                    if (ksel != SENT) {               // first valid = true min outgoing
                        const int j  = (int)(ksel & 0xFFFFFFFFu);
                        const u32 wm = (u32)(ksel >> 32);
                        const int lo = rw < j ? rw : j, hi = rw < j ? j : rw;
                        atomicMin(&mk[g * N + c_r], ((u64)wm << 24) | ((u64)lo << 12) | (u64)hi);
                    } else if (!end) {                // 8 real cands, all internal -> rescan
                        s_stale[atomicAdd(&s_stalecnt, 1)] = (unsigned short)rw;
                    }
                }
            }
            __syncthreads();

            // rescan stale rows: wave wid handles s_stale[wid]
            if (wid < s_stalecnt) {
                const int rw  = s_stale[wid];
                const int c_r = (int)u.scan.cmp[rw];
                const int rii = (int)((u.scan.ints[rw >> 2] >> ((rw & 3) * 8)) & 255u);
                const float* Sr = S + (size_t)rw * N;
                u64 best = SENT;
                for (int k = 0; k < 16; ++k) {
                    const float4 f4 = *(const float4*)(Sr + k * 256 + lane * 4);
                    const u32 ip  = u.scan.ints[k * 64 + lane];
                    const u32 cp0 = ((const u32*)u.scan.cmp)[k * 128 + lane * 2];
                    const u32 cp1 = ((const u32*)u.scan.cmp)[k * 128 + lane * 2 + 1];
                    const float sv[4] = {f4.x, f4.y, f4.z, f4.w};
                    #pragma unroll
                    for (int m = 0; m < 4; ++m) {
                        const int j  = k * 256 + lane * 4 + m;
                        const int cj = (int)(((m < 2) ? (cp0 >> (16 * m)) : (cp1 >> (16 * (m - 2)))) & 0xFFFFu);
                        if (cj == c_r) continue;
                        const bool eq = (int)((ip >> (8 * m)) & 255u) == rii;
                        float w2; bool ex;
                        if (g == 0) { w2 = -sv[m]; ex = eq && (sv[m] != 0.0f); }
                        else { const float v = (sv[m] + (eq ? 0.0f : 0.5f)) - (eq ? 1.0f : 0.0f);
                               w2 = -v; ex = (v > 0.0f); }
                        if (!ex || j == rw) continue;
                        const u64 kk2 = ((u64)mapf(w2) << 32) | (u32)j;
                        if (kk2 < best) best = kk2;
                    }
                }
                #pragma unroll
                for (int d2 = 1; d2 < 64; d2 <<= 1) { const u64 o = __shfl_xor(best, d2, 64); if (o < best) best = o; }
                if (lane == 0 && best != SENT) {
                    const int j  = (int)(best & 0xFFFFFFFFu);
                    const u32 wm = (u32)(best >> 32);
                    const int lo = rw < j ? rw : j, hi = rw < j ? j : rw;
                    atomicMin(&mk[g * N + c_r], ((u64)wm << 24) | ((u64)lo << 12) | (u64)hi);
                }
            }
            __syncthreads();
        }
        __threadfence(); grid.sync(); __threadfence();

        // merge: block 0 -> gold, block 1 -> viol (r7-proven star contraction)
        if (bid < 2 && !(bid ? d1 : d0)) {
            const int g = bid;
            int* cgp = comp + g * N;
            u64* mkg = mk + g * N;
            int e_before = 0;
            if (tid == 0) e_before = s_ecnt;
            // phase 1: parent pointers (atomic read of mk dodges L1 staleness)
            for (int c = tid; c < N; c += NT) {
                const u64 k = atomicMin(&mkg[c], SENT);
                int p = c;
                if (k == SENT) { finalf[g * N + c] = 1; }
                else {
                    const int lo = (int)((k >> 12) & 4095u), hi = (int)(k & 4095u);
                    const int clo = cgp[lo], chi = cgp[hi];
                    p = (clo == c) ? chi : clo;
                }
                u.merge.par[c] = p;
            }
            __syncthreads();
            // phase 2: break mutual pairs (smaller index becomes root)
            for (int c = tid; c < N; c += NT) {
                const int d = u.merge.par[c];
                if (d != c && u.merge.par[d] == c && c < d) u.merge.par[c] = c;
            }
            __syncthreads();
            // phase 3: dedupe + append edges to LDS list
            for (int c = tid; c < N; c += NT) {
                const u64 k = atomicMin(&mkg[c], SENT);
                if (k == SENT) continue;
                const int lo = (int)((k >> 12) & 4095u), hi = (int)(k & 4095u);
                const int clo = cgp[lo], chi = cgp[hi];
                const int d = (clo == c) ? chi : clo;
                const u64 kd = atomicMin(&mkg[d], SENT);
                const bool dup = (kd == k) && (d < c);
                if (!dup) { const int idx = atomicAdd(&s_ecnt, 1); if (idx < EDGE_CAP) s_edge[idx] = k; }
            }
            __syncthreads();
            // phase 4: pointer jumping
            for (int it = 0; it < 12; ++it) {
                for (int c = tid; c < N; c += NT) u.merge.par[c] = u.merge.par[u.merge.par[c]];
                __syncthreads();
            }
            // phase 5: relabel + reset mk
            for (int i2 = tid; i2 < N; i2 += NT) {
                cgp[i2] = u.merge.par[cgp[i2]];
                mkg[i2] = SENT;
            }
            __syncthreads();
            if (tid == 0 && s_ecnt == e_before) done[g] = 1;   // no merges -> done
        }
        __threadfence(); grid.sync(); __threadfence();
    }

    // ---------------- count (node-0's final component only) ----------------
    if (bid < 2) {
        const int g = bid;
        const int n = (s_ecnt < EDGE_CAP) ? s_ecnt : EDGE_CAP;
        const int r0c = comp[g * N + 0];
        double A = 0.0, B = 0.0, W = 0.0;
        for (int e = tid; e < n; e += NT) {
            const u64 k = s_edge[e];
            const int lo = (int)((k >> 12) & 4095u), hi = (int)(k & 4095u);
            if (comp[g * N + lo] != r0c) continue;
            const float w2 = unmapf((u32)(k >> 24));
            if (g == 0) A += 1.0;
            else { if (intents[lo] == intents[hi]) A += 1.0; else B += 1.0; }
            W += (double)w2;
        }
        #pragma unroll
        for (int d2 = 1; d2 < 64; d2 <<= 1) {
            A += __shfl_xor(A, d2, 64); B += __shfl_xor(B, d2, 64); W += __shfl_xor(W, d2, 64);
        }
        if (lane == 0) { s_red[wid][0] = A; s_red[wid][1] = B; s_red[wid][2] = W; }
        __syncthreads();
        if (tid == 0) {
            double a = 0, b = 0, w2 = 0;
            for (int q = 0; q < 16; ++q) { a += s_red[q][0]; b += s_red[q][1]; w2 += s_red[q][2]; }
            stats[g * 3 + 0] = a; stats[g * 3 + 1] = b; stats[g * 3 + 2] = w2;
        }
    }
    __threadfence(); grid.sync(); __threadfence();

    // ---------------- finalize ----------------
    if (bid == 0 && tid == 0) {
        const double a = stats[0], sum_g = stats[2];
        const double b = stats[3], c = stats[4], sum_v = stats[5];
        const double gold_score = -sum_g;                 // S = -w
        const double viol_score = -sum_v + b - 0.5 * c;   // S = -w + eq - 0.5*neq
        const double delta = a - b + 0.5 * c;             // C=1, R=0.5
        const double obj   = delta + viol_score - gold_score;
        out[0] = (float)((delta > 0.0) ? fmax(0.0, obj) : 0.0);
    }
}

extern "C" void kernel_launch(void* const* d_in, const int* in_sizes, int n_in,
                              void* d_out, int out_size, void* d_ws, size_t ws_size,
                              hipStream_t stream)
{
    const float* S       = (const float*)d_in[0];
    const int*   intents = (const int*)d_in[1];
    float*       out     = (float*)d_out;

    char* w = (char*)d_ws;
    double* stats = (double*)w;                               // 64 B
    u64*    mk    = (u64*)(w + 64);                           // 2*N*8   = 64 KiB
    u64*    cand  = (u64*)(w + 64 + 2 * N * 8);               // 2*N*8*8 = 512 KiB
    int*    comp  = (int*)(w + 64 + 2 * N * 8 + 2 * N * 8 * 8);
    int*    finalf = comp + 2 * N;
    int*    done   = finalf + 2 * N;

    void* args[] = { (void*)&S, (void*)&intents, (void*)&stats, (void*)&mk,
                     (void*)&cand, (void*)&comp, (void*)&finalf, (void*)&done, (void*)&out };
    hipError_t err = hipLaunchCooperativeKernel((const void*)sc_loss_kernel,
                                                dim3(NB), dim3(NT), args, 0, stream);
    (void)err;
}

// Round 11
// 323.136 us; speedup vs baseline: 7.6420x; 7.6420x over previous
//
#include <hip/hip_runtime.h>
#include <math.h>

typedef unsigned long long u64;
typedef unsigned int u32;

// SupervisedClusteringLoss via Borůvka MST, multi-launch (r7-proven skeleton)
// + candidate lists (r9-proven logic). r7 counters: scan was LDS-bank-conflict
// bound (2.86M/scan) and re-read the matrix every round (33MB HBM/scan).
// r9 coop single-kernel regressed 7.5x (grid.sync + serialized merge) -> back
// to separate kernels: build top-8 cand lists once (conflict-free packing),
// rounds resolve from cand lists; rare all-internal rows rescan from L3.
// Loss invariance: any MST under strict total order (w,lo,hi) has the same
// weight multiset; obj depends only on weights (r7/r9: absmax 0.0).

constexpr int N        = 4096;
constexpr int EDGE_CAP = 4608;
constexpr int ROUNDS   = 12;
constexpr u64 SENT     = ~0ull;

__device__ __forceinline__ u32 mapf(float f) {
    u32 u = __float_as_uint(f);
    return (u & 0x80000000u) ? ~u : (u | 0x80000000u);
}
__device__ __forceinline__ float unmapf(u32 m) {
    u32 u = (m & 0x80000000u) ? (m ^ 0x80000000u) : ~m;
    return __uint_as_float(u);
}

#define INS_STEP(ci) { u64 lo = (ci < t) ? ci : t; u64 hi = (ci < t) ? t : ci; ci = lo; t = hi; }

__global__ __launch_bounds__(1024, 1)
void bv_init(double* stats, u64* mk, int* comp, int* finalf,
             int* goldact, int* edgecnt, int* done)
{
    const int t = blockIdx.x * 1024 + threadIdx.x;   // grid 8 -> 8192 threads
    if (t < 2 * N) { mk[t] = SENT; comp[t] = t & (N - 1); finalf[t] = 0; }
    if (t < 256) goldact[t] = 0;
    if (t < 8) stats[t] = 0.0;
    if (t < 2) { edgecnt[t] = 0; done[t] = 0; }
}

// One full matrix pass: per-row sorted top-8 candidate list (one wave/row).
__global__ __launch_bounds__(1024, 1)
void bv_build(const float* __restrict__ S, const int* __restrict__ intents,
              u64* __restrict__ cand, int* __restrict__ goldact)
{
    const int g   = blockIdx.y;
    const int tid = threadIdx.x, lane = tid & 63, wid = tid >> 6;
    __shared__ u32 s_ints[N / 4];                    // intents packed u8x4
    for (int d = tid; d < N / 4; d += 1024) {
        const int4 v = *(const int4*)(intents + 4 * d);
        s_ints[d] = (u32)(v.x & 255) | ((u32)(v.y & 255) << 8) |
                    ((u32)(v.z & 255) << 16) | ((u32)(v.w & 255) << 24);
    }
    __syncthreads();
    const int i0   = (int)(s_ints[0] & 255u);
    const int row  = blockIdx.x * 16 + wid;
    const int myii = (int)((s_ints[row >> 2] >> ((row & 3) * 8)) & 255u);
    u64* cp = cand + ((size_t)(g * N + row)) * 8;

    if (g == 0) {
        if (myii == i0) { if (lane == 0) goldact[blockIdx.x] = 1; }
        else {
            if (lane == 0) {
                #pragma unroll
                for (int i = 0; i < 8; ++i) cp[i] = SENT;
            }
            return;
        }
    }
    const float* Srow = S + (size_t)row * N;
    u64 c0=SENT,c1=SENT,c2=SENT,c3=SENT,c4=SENT,c5=SENT,c6=SENT,c7=SENT;
    for (int k = 0; k < 16; ++k) {
        const float4 f4 = *(const float4*)(Srow + k * 256 + lane * 4);
        const u32 ip    = s_ints[k * 64 + lane];     // stride-1 -> conflict-free
        const float sv[4] = {f4.x, f4.y, f4.z, f4.w};
        #pragma unroll
        for (int m = 0; m < 4; ++m) {
            const int j   = k * 256 + lane * 4 + m;
            const bool eq = (int)((ip >> (8 * m)) & 255u) == myii;
            float w2; bool ex;
            if (g == 0) { w2 = -sv[m]; ex = eq && (sv[m] != 0.0f); }
            else { const float v = (sv[m] + (eq ? 0.0f : 0.5f)) - (eq ? 1.0f : 0.0f);
                   w2 = -v; ex = (v > 0.0f); }
            ex = ex && (j != row);
            const u64 key = ex ? (((u64)mapf(w2) << 32) | (u32)j) : SENT;
            if (key < c7) {                          // streaming sorted top-8 insert
                u64 t = key;
                INS_STEP(c0) INS_STEP(c1) INS_STEP(c2) INS_STEP(c3)
                INS_STEP(c4) INS_STEP(c5) INS_STEP(c6) INS_STEP(c7)
            }
        }
    }
    // extract wave-global top-8 ascending (unique keys -> exactly one popper)
    #pragma unroll
    for (int i = 0; i < 8; ++i) {
        u64 m = c0;
        #pragma unroll
        for (int d2 = 1; d2 < 64; d2 <<= 1) { const u64 o = __shfl_xor(m, d2, 64); if (o < m) m = o; }
        if (c0 == m) { c0=c1; c1=c2; c2=c3; c3=c4; c4=c5; c5=c6; c6=c7; c7=SENT; }
        if (lane == 0) cp[i] = m;
    }
}

// Round scan from cand lists; all-internal rows rescan their matrix row (L3).
__global__ __launch_bounds__(1024, 1)
void bv_cscan(const float* __restrict__ S, const int* __restrict__ intents,
              const u64* __restrict__ cand, u64* __restrict__ mk,
              const int* __restrict__ comp, const int* __restrict__ finalf,
              const int* __restrict__ goldact, const int* __restrict__ done)
{
    const int g = blockIdx.y;
    if (done[g]) return;
    if (g == 0 && !goldact[blockIdx.x]) return;      // no class-0 rows here
    const int tid = threadIdx.x, lane = tid & 63, wid = tid >> 6;

    __shared__ unsigned short s_cmp[N];              // comp packed u16
    __shared__ u32 s_ints[N / 4];                    // intents packed u8x4
    __shared__ int s_stalecnt;
    __shared__ unsigned short s_stale[16];
    for (int d = tid; d < N / 2; d += 1024) {
        const int2 cpr = *(const int2*)(comp + g * N + 2 * d);
        ((u32*)s_cmp)[d] = (u32)(cpr.x & 0xFFFF) | ((u32)(cpr.y & 0xFFFF) << 16);
    }
    for (int d = tid; d < N / 4; d += 1024) {
        const int4 v = *(const int4*)(intents + 4 * d);
        s_ints[d] = (u32)(v.x & 255) | ((u32)(v.y & 255) << 8) |
                    ((u32)(v.z & 255) << 16) | ((u32)(v.w & 255) << 24);
    }
    if (tid == 0) s_stalecnt = 0;
    __syncthreads();

    // cand-scan: thread t<16 owns row blockIdx.x*16+t
    if (tid < 16) {
        const int rw  = blockIdx.x * 16 + tid;
        const int c_r = (int)s_cmp[rw];
        if (!finalf[g * N + c_r]) {
            const u64* cp = cand + ((size_t)(g * N + rw)) * 8;
            u64 ksel = SENT; bool end = false;
            #pragma unroll
            for (int i = 0; i < 8; ++i) {
                const u64 k = cp[i];
                const bool isS = (k == SENT);
                if (!end && !isS && ksel == SENT) {
                    const int j = (int)(k & 0xFFFFFFFFu);
                    if ((int)s_cmp[j] != c_r) ksel = k;   // first cross-comp = true min
                }
                end = end || isS;
            }
            if (ksel != SENT) {
                const int j  = (int)(ksel & 0xFFFFFFFFu);
                const u32 wm = (u32)(ksel >> 32);
                const int lo = rw < j ? rw : j, hi = rw < j ? j : rw;
                atomicMin(&mk[g * N + c_r], ((u64)wm << 24) | ((u64)lo << 12) | (u64)hi);
            } else if (!end) {                       // 8 real cands, all internal
                s_stale[atomicAdd(&s_stalecnt, 1)] = (unsigned short)rw;
            }
        }
    }
    __syncthreads();

    // rescan stale rows: wave wid handles s_stale[wid] (matrix row from L3)
    if (wid < s_stalecnt) {
        const int rw  = s_stale[wid];
        const int c_r = (int)s_cmp[rw];
        const int rii = (int)((s_ints[rw >> 2] >> ((rw & 3) * 8)) & 255u);
        const float* Sr = S + (size_t)rw * N;
        u64 best = SENT;
        for (int k = 0; k < 16; ++k) {
            const float4 f4 = *(const float4*)(Sr + k * 256 + lane * 4);
            const u32 ip  = s_ints[k * 64 + lane];
            const u32 cp0 = ((const u32*)s_cmp)[k * 128 + lane * 2];
            const u32 cp1 = ((const u32*)s_cmp)[k * 128 + lane * 2 + 1];
            const float sv[4] = {f4.x, f4.y, f4.z, f4.w};
            #pragma unroll
            for (int m = 0; m < 4; ++m) {
                const int j  = k * 256 + lane * 4 + m;
                const int cj = (int)(((m < 2) ? (cp0 >> (16 * m)) : (cp1 >> (16 * (m - 2)))) & 0xFFFFu);
                if (cj == c_r) continue;
                const bool eq = (int)((ip >> (8 * m)) & 255u) == rii;
                float w2; bool ex;
                if (g == 0) { w2 = -sv[m]; ex = eq && (sv[m] != 0.0f); }
                else { const float v = (sv[m] + (eq ? 0.0f : 0.5f)) - (eq ? 1.0f : 0.0f);
                       w2 = -v; ex = (v > 0.0f); }
                if (!ex || j == rw) continue;
                const u64 kk2 = ((u64)mapf(w2) << 32) | (u32)j;
                if (kk2 < best) best = kk2;
            }
        }
        #pragma unroll
        for (int d2 = 1; d2 < 64; d2 <<= 1) { const u64 o = __shfl_xor(best, d2, 64); if (o < best) best = o; }
        if (lane == 0 && best != SENT) {
            const int j  = (int)(best & 0xFFFFFFFFu);
            const u32 wm = (u32)(best >> 32);
            const int lo = rw < j ? rw : j, hi = rw < j ? j : rw;
            atomicMin(&mk[g * N + c_r], ((u64)wm << 24) | ((u64)lo << 12) | (u64)hi);
        }
    }
}

// Star contraction (r7 verbatim — absmax 0.0 proven).
__global__ __launch_bounds__(1024, 1)
void bv_merge(u64* __restrict__ minkey, int* __restrict__ comp,
              int* __restrict__ finalf, u64* __restrict__ edgebuf,
              int* __restrict__ edgecnt, int* __restrict__ done)
{
    const int g = blockIdx.x;
    if (done[g]) return;
    const int tid = threadIdx.x;
    __shared__ int s_par[N];
    __shared__ int s_oth[N];
    __shared__ int s_merged;
    if (tid == 0) s_merged = 0;
    u64* mk = minkey + g * N;
    int* cg = comp + g * N;
    __syncthreads();

    for (int c = tid; c < N; c += 1024) {
        const u64 k = mk[c];
        if (k == SENT) { s_par[c] = c; s_oth[c] = c; finalf[g * N + c] = 1; }
        else {
            const int lo = (int)((k >> 12) & 4095u), hi = (int)(k & 4095u);
            const int clo = cg[lo], chi = cg[hi];
            const int d = (clo == c) ? chi : clo;
            s_par[c] = d; s_oth[c] = d;
        }
    }
    __syncthreads();
    for (int c = tid; c < N; c += 1024) {
        const int d = s_par[c];
        if (d != c && s_par[d] == c && c < d) s_par[c] = c;
    }
    __syncthreads();
    for (int c = tid; c < N; c += 1024) {
        const u64 k = mk[c];
        if (k == SENT) continue;
        s_merged = 1;
        const int d = s_oth[c];
        const bool dup = (mk[d] == k) && (d < c);
        if (!dup) { const int idx = atomicAdd(&edgecnt[g], 1); if (idx < EDGE_CAP) edgebuf[g * EDGE_CAP + idx] = k; }
    }
    __syncthreads();
    for (int r = 0; r < 12; ++r) {
        for (int c = tid; c < N; c += 1024) s_par[c] = s_par[s_par[c]];
        __syncthreads();
    }
    for (int i2 = tid; i2 < N; i2 += 1024) { cg[i2] = s_par[cg[i2]]; mk[i2] = SENT; }
    if (tid == 0 && !s_merged) done[g] = 1;
}

__global__ __launch_bounds__(1024, 1)
void bv_count(const int* __restrict__ intents, const u64* __restrict__ edgebuf,
              const int* __restrict__ edgecnt, const int* __restrict__ comp,
              double* __restrict__ stats)
{
    const int g = blockIdx.x;
    const int tid = threadIdx.x, lane = tid & 63, wid = tid >> 6;
    __shared__ double s_acc[16][3];
    int n = edgecnt[g]; if (n > EDGE_CAP) n = EDGE_CAP;
    const int r0 = comp[g * N + 0];
    double A = 0.0, B = 0.0, W = 0.0;
    for (int e = tid; e < n; e += 1024) {
        const u64 k = edgebuf[g * EDGE_CAP + e];
        const int lo = (int)((k >> 12) & 4095u), hi = (int)(k & 4095u);
        if (comp[g * N + lo] != r0) continue;
        const float w = unmapf((u32)(k >> 24));
        if (g == 0) A += 1.0;
        else { if (intents[lo] == intents[hi]) A += 1.0; else B += 1.0; }
        W += (double)w;
    }
    #pragma unroll
    for (int d = 1; d < 64; d <<= 1) {
        A += __shfl_xor(A, d, 64); B += __shfl_xor(B, d, 64); W += __shfl_xor(W, d, 64);
    }
    if (lane == 0) { s_acc[wid][0] = A; s_acc[wid][1] = B; s_acc[wid][2] = W; }
    __syncthreads();
    if (tid == 0) {
        double a = 0, b = 0, w = 0;
        for (int q = 0; q < 16; ++q) { a += s_acc[q][0]; b += s_acc[q][1]; w += s_acc[q][2]; }
        stats[g * 3 + 0] = a; stats[g * 3 + 1] = b; stats[g * 3 + 2] = w;
    }
}

__global__ void finalize_kernel(const double* __restrict__ ws, float* __restrict__ out)
{
    const double a = ws[0], sum_g = ws[2];
    const double b = ws[3], c = ws[4], sum_v = ws[5];
    const double gold_score = -sum_g;                 // S = -w
    const double viol_score = -sum_v + b - 0.5 * c;   // S = -w + eq - 0.5*neq
    const double delta = a - b + 0.5 * c;             // C=1, R=0.5
    const double obj   = delta + viol_score - gold_score;
    out[0] = (float)((delta > 0.0) ? fmax(0.0, obj) : 0.0);
}

extern "C" void kernel_launch(void* const* d_in, const int* in_sizes, int n_in,
                              void* d_out, int out_size, void* d_ws, size_t ws_size,
                              hipStream_t stream)
{
    const float* S       = (const float*)d_in[0];
    const int*   intents = (const int*)d_in[1];
    float*       out     = (float*)d_out;

    char* w = (char*)d_ws;
    double* stats   = (double*)w;                                 // 64 B
    u64*    mk      = (u64*)(w + 64);                             // 64 KiB
    u64*    cand    = (u64*)(w + 64 + 2 * N * 8);                 // 512 KiB
    u64*    edgebuf = (u64*)(w + 64 + 2 * N * 8 + 2 * N * 8 * 8); // 72 KiB
    int*    comp    = (int*)(w + 64 + 2 * N * 8 + 2 * N * 8 * 8 + 2 * EDGE_CAP * 8);
    int*    finalf  = comp + 2 * N;
    int*    goldact = finalf + 2 * N;
    int*    edgecnt = goldact + 256;
    int*    done    = edgecnt + 2;

    hipLaunchKernelGGL(bv_init, dim3(8), dim3(1024), 0, stream,
                       stats, mk, comp, finalf, goldact, edgecnt, done);
    hipLaunchKernelGGL(bv_build, dim3(256, 2), dim3(1024), 0, stream,
                       S, intents, cand, goldact);
    for (int r = 0; r < ROUNDS; ++r) {
        hipLaunchKernelGGL(bv_cscan, dim3(256, 2), dim3(1024), 0, stream,
                           S, intents, cand, mk, comp, finalf, goldact, done);
        hipLaunchKernelGGL(bv_merge, dim3(2), dim3(1024), 0, stream,
                           mk, comp, finalf, edgebuf, edgecnt, done);
    }
    hipLaunchKernelGGL(bv_count, dim3(2), dim3(1024), 0, stream,
                       intents, edgebuf, edgecnt, comp, stats);
    hipLaunchKernelGGL(finalize_kernel, dim3(1), dim3(1), 0, stream, stats, out);
}